// Round 6
// baseline (1033.944 us; speedup 1.0000x reference)
//
#include <hip/hip_runtime.h>
#include <stdint.h>
#include <math.h>

// ---------------------------------------------------------------------------
// HippocampalFastWeight on MI355X (gfx950)
// B=8, T=2048, D=512, N=2048, K_CA3=64
// Round 6: ballot-based barrier-free top-k (replaces LDS-atomic radix
// histogram whose same-exponent-bin atomics serialized: 3.5e7 conflict
// cycles, 233 us). Each wave loads the full 2048-key row and finds the
// exact 64th-largest bf16 key via 15-iter binary search with
// v_cmp+ballot+popc (wave-uniform, no LDS). Tie order via mbcnt.
// GEMM pipeline unchanged from round 5 (fp8 gram/succ, bf16 h/gate).
// ---------------------------------------------------------------------------

typedef __attribute__((ext_vector_type(8))) short bf16x8;
typedef __attribute__((ext_vector_type(8))) unsigned short u16x8;
typedef __attribute__((ext_vector_type(8))) unsigned char u8x8;
typedef __attribute__((ext_vector_type(4))) float f32x4;

#define GLD_LDS16(gp, lp)                                     \
  __builtin_amdgcn_global_load_lds(                           \
      (const __attribute__((address_space(1))) void*)(gp),    \
      (__attribute__((address_space(3))) void*)(lp), 16, 0, 0)

__device__ __forceinline__ uint16_t f2bf(float f) {
  uint32_t u = __float_as_uint(f);
  uint32_t r = u + 0x7FFFu + ((u >> 16) & 1u);
  return (uint16_t)(r >> 16);
}
__device__ __forceinline__ float bf2f(unsigned u) {
  return __uint_as_float(u << 16);
}

// f32 -> fp8 e4m3fn (inputs non-negative, < 448 here)
__device__ __forceinline__ uint8_t f2fp8(float f) {
#if __has_builtin(__builtin_amdgcn_cvt_pk_fp8_f32)
  return (uint8_t)(__builtin_amdgcn_cvt_pk_fp8_f32(f, 0.f, 0, false) & 0xFF);
#else
  if (!(f > 0.f)) return 0;
  if (f >= 448.f) return 0x7E;
  uint32_t u = __float_as_uint(f);
  int e = (int)((u >> 23) & 255) - 127;
  uint32_t m = u & 0x7FFFFFu;
  if (e < -6) {
    float q = f * 512.f;
    int qi = (int)(q + 0.5f);
    if (qi > 7) return 0x08;
    return (uint8_t)qi;
  }
  uint32_t keep = m >> 20;
  uint32_t rem = m & 0xFFFFFu;
  if (rem > 0x80000u || (rem == 0x80000u && (keep & 1))) keep++;
  uint32_t ee = (uint32_t)(e + 7);
  if (keep == 8) { keep = 0; ee++; }
  if (ee >= 16) return 0x7E;
  return (uint8_t)((ee << 3) | keep);
#endif
}

// bits of 64-bit mask strictly below this lane
__device__ __forceinline__ int bits_below(unsigned long long m) {
  return __builtin_amdgcn_mbcnt_hi((unsigned)(m >> 32),
                                   __builtin_amdgcn_mbcnt_lo((unsigned)m, 0));
}

// ------------------------------- cast --------------------------------------
__global__ __launch_bounds__(256) void cast_f32_bf16_k(
    const float* __restrict__ s, uint16_t* __restrict__ d, long long n) {
  long long i = (long long)blockIdx.x * 256 + threadIdx.x;
  long long stride = (long long)gridDim.x * 256;
  for (; i < n; i += stride) d[i] = f2bf(s[i]);
}

__global__ __launch_bounds__(256) void zero_f32_k(float* __restrict__ p, long long n) {
  long long i = (long long)blockIdx.x * 256 + threadIdx.x;
  if (i < n) p[i] = 0.f;
}

// ------------- transpose up_W (D x N fp32 -> N x D bf16) -------------------
__global__ __launch_bounds__(256) void transpose_upw_k(
    const float* __restrict__ src, uint16_t* __restrict__ dst, int D, int N) {
  __shared__ float t[32][33];
  int n0 = blockIdx.x * 32, d0 = blockIdx.y * 32;
  int lx = threadIdx.x & 31, ly = threadIdx.x >> 5;
#pragma unroll
  for (int r = 0; r < 4; ++r) {
    int d = d0 + ly + r * 8;
    t[ly + r * 8][lx] = src[(long long)d * N + n0 + lx];
  }
  __syncthreads();
#pragma unroll
  for (int r = 0; r < 4; ++r) {
    int n = n0 + ly + r * 8;
    dst[(long long)n * D + d0 + lx] = f2bf(t[lx][ly + r * 8]);
  }
}

// --------------------------- bf16 GEMM -------------------------------------
#define EPI_RELU_BF16 0
#define EPI_SIG 2

template <int EPI>
__global__ __launch_bounds__(256) void gemm_bt_k(
    const uint16_t* __restrict__ A, const uint16_t* __restrict__ B,
    void* __restrict__ Cv, const float* __restrict__ bias,
    int M, int N, int K) {
  __shared__ __align__(16) uint16_t As[128 * 32];
  __shared__ __align__(16) uint16_t Bs[128 * 32];
  const int tid = threadIdx.x;
  const int lane = tid & 63;
  const int wave = tid >> 6;
  const int m0 = blockIdx.x * 128;
  const int n0 = blockIdx.y * 128;
  const int wm = (wave & 1) * 64;
  const int wn = (wave >> 1) * 64;
  const int quad = lane >> 4;
  const int l16 = lane & 15;

  f32x4 acc[4][4];
#pragma unroll
  for (int i = 0; i < 4; ++i)
#pragma unroll
    for (int j = 0; j < 4; ++j) acc[i][j] = (f32x4){0.f, 0.f, 0.f, 0.f};

  const int srow = wave * 16 + (lane >> 2);
  const int sseg = lane & 3;
  const long long arow0 = (long long)(m0 + srow) * K + sseg * 8;
  const long long brow0 = (long long)(n0 + srow) * K + sseg * 8;

  for (int k0 = 0; k0 < K; k0 += 32) {
#pragma unroll
    for (int r = 0; r < 2; ++r) {
      GLD_LDS16(A + arow0 + (long long)r * 64 * K + k0,
                &As[(r * 64 + wave * 16) * 32]);
      GLD_LDS16(B + brow0 + (long long)r * 64 * K + k0,
                &Bs[(r * 64 + wave * 16) * 32]);
    }
    __syncthreads();
    bf16x8 af[4], bfr[4];
#pragma unroll
    for (int i = 0; i < 4; ++i)
      af[i] = *(const bf16x8*)(&As[(wm + i * 16 + l16) * 32 + quad * 8]);
#pragma unroll
    for (int j = 0; j < 4; ++j)
      bfr[j] = *(const bf16x8*)(&Bs[(wn + j * 16 + l16) * 32 + quad * 8]);
#pragma unroll
    for (int i = 0; i < 4; ++i)
#pragma unroll
      for (int j = 0; j < 4; ++j)
        acc[i][j] = __builtin_amdgcn_mfma_f32_16x16x32_bf16(af[i], bfr[j], acc[i][j], 0, 0, 0);
    __syncthreads();
  }

#pragma unroll
  for (int i = 0; i < 4; ++i) {
#pragma unroll
    for (int j = 0; j < 4; ++j) {
#pragma unroll
      for (int r = 0; r < 4; ++r) {
        int row = m0 + wm + i * 16 + quad * 4 + r;
        int col = n0 + wn + j * 16 + l16;
        float v = acc[i][j][r];
        if (EPI == EPI_RELU_BF16) {
          uint16_t* C = (uint16_t*)Cv;
          C[(long long)row * N + col] = f2bf(v > 0.f ? v : 0.f);
        } else {
          float* C = (float*)Cv;
          float z = v + bias[col];
          C[(long long)row * N + col] = 1.f / (1.f + __expf(-z));
        }
      }
    }
  }
}

// --------------------- fp8 Gram GEMM: G = S·S^T ----------------------------
__global__ __launch_bounds__(256) void gram_fp8_k(
    const uint8_t* __restrict__ S, uint8_t* __restrict__ G,
    long long sS, long long sG) {
  __shared__ __align__(16) uint8_t As[128 * 32];
  __shared__ __align__(16) uint8_t Bs[128 * 32];
  const int b = blockIdx.z;
  const uint8_t* Sb = S + (long long)b * sS;
  uint8_t* Gb = G + (long long)b * sG;
  int idx = blockIdx.x;
  int ti = 0;
  while ((ti + 1) * (ti + 2) / 2 <= idx) ti++;
  int tj = idx - ti * (ti + 1) / 2;
  const int m0 = ti * 128;
  const int n0 = tj * 128;
  const int tid = threadIdx.x;
  const int lane = tid & 63;
  const int wave = tid >> 6;
  const int wm = (wave & 1) * 64;
  const int wn = (wave >> 1) * 64;
  const int quad = lane >> 4;
  const int l16 = lane & 15;
  const int K = 2048, T = 2048;

  f32x4 acc[4][4];
#pragma unroll
  for (int i = 0; i < 4; ++i)
#pragma unroll
    for (int j = 0; j < 4; ++j) acc[i][j] = (f32x4){0.f, 0.f, 0.f, 0.f};

  const int srow = wave * 32 + (lane >> 1);
  const int shalf = lane & 1;
  const long long arow0 = (long long)(m0 + srow) * K + shalf * 16;
  const long long brow0 = (long long)(n0 + srow) * K + shalf * 16;

  for (int k0 = 0; k0 < K; k0 += 32) {
    GLD_LDS16(Sb + arow0 + k0, &As[wave * 1024]);
    GLD_LDS16(Sb + brow0 + k0, &Bs[wave * 1024]);
    __syncthreads();
    long af[4], bfr[4];
#pragma unroll
    for (int i = 0; i < 4; ++i)
      af[i] = *(const long*)(&As[(wm + i * 16 + l16) * 32 + quad * 8]);
#pragma unroll
    for (int j = 0; j < 4; ++j)
      bfr[j] = *(const long*)(&Bs[(wn + j * 16 + l16) * 32 + quad * 8]);
#pragma unroll
    for (int i = 0; i < 4; ++i)
#pragma unroll
      for (int j = 0; j < 4; ++j)
        acc[i][j] = __builtin_amdgcn_mfma_f32_16x16x32_fp8_fp8(af[i], bfr[j], acc[i][j], 0, 0, 0);
    __syncthreads();
  }

#pragma unroll
  for (int i = 0; i < 4; ++i) {
#pragma unroll
    for (int j = 0; j < 4; ++j) {
      uint8_t bv[4];
#pragma unroll
      for (int r = 0; r < 4; ++r) {
        int row = m0 + wm + i * 16 + quad * 4 + r;
        int col = n0 + wn + j * 16 + l16;
        uint8_t h = f2fp8(acc[i][j][r]);
        bv[r] = h;
        Gb[(long long)row * T + col] = h;
      }
      if (ti != tj) {
        int mrow = n0 + wn + j * 16 + l16;
        int mcol = m0 + wm + i * 16 + quad * 4;
        uchar4 pk = {bv[0], bv[1], bv[2], bv[3]};
        *(uchar4*)(&Gb[(long long)mrow * T + mcol]) = pk;
      }
    }
  }
}

// ------------------- fp8 succ GEMM: succ = relu(G@STs^T - S*wd) ------------
__global__ __launch_bounds__(256) void succ_fp8_k(
    const uint8_t* __restrict__ G, const uint8_t* __restrict__ STs,
    uint16_t* __restrict__ C, const float* __restrict__ wd,
    long long sG, long long sB, long long sC) {
  __shared__ __align__(16) uint8_t As[128 * 32];
  __shared__ __align__(16) uint8_t Bs[128 * 32];
  const int b = blockIdx.z;
  const uint8_t* Ab = G + (long long)b * sG;
  const uint8_t* Bb = STs + (long long)b * sB;
  uint16_t* Cb = C + (long long)b * sC;
  const float* wdb = wd + (long long)b * 2048;
  const int tid = threadIdx.x;
  const int lane = tid & 63;
  const int wave = tid >> 6;
  const int m0 = blockIdx.x * 128;
  const int n0 = blockIdx.y * 128;
  const int wm = (wave & 1) * 64;
  const int wn = (wave >> 1) * 64;
  const int quad = lane >> 4;
  const int l16 = lane & 15;
  const int K = 2048, N = 2048;

  f32x4 acc[4][4];
#pragma unroll
  for (int i = 0; i < 4; ++i)
#pragma unroll
    for (int j = 0; j < 4; ++j) acc[i][j] = (f32x4){0.f, 0.f, 0.f, 0.f};

  const int srow = wave * 32 + (lane >> 1);
  const int shalf = lane & 1;
  const long long arow0 = (long long)(m0 + srow) * K + shalf * 16;
  const long long brow0 = (long long)(n0 + srow) * K + shalf * 16;

  for (int k0 = 0; k0 < K; k0 += 32) {
    GLD_LDS16(Ab + arow0 + k0, &As[wave * 1024]);
    GLD_LDS16(Bb + brow0 + k0, &Bs[wave * 1024]);
    __syncthreads();
    long af[4], bfr[4];
#pragma unroll
    for (int i = 0; i < 4; ++i)
      af[i] = *(const long*)(&As[(wm + i * 16 + l16) * 32 + quad * 8]);
#pragma unroll
    for (int j = 0; j < 4; ++j)
      bfr[j] = *(const long*)(&Bs[(wn + j * 16 + l16) * 32 + quad * 8]);
#pragma unroll
    for (int i = 0; i < 4; ++i)
#pragma unroll
      for (int j = 0; j < 4; ++j)
        acc[i][j] = __builtin_amdgcn_mfma_f32_16x16x32_fp8_fp8(af[i], bfr[j], acc[i][j], 0, 0, 0);
    __syncthreads();
  }

#pragma unroll
  for (int i = 0; i < 4; ++i) {
#pragma unroll
    for (int j = 0; j < 4; ++j) {
#pragma unroll
      for (int r = 0; r < 4; ++r) {
        int row = m0 + wm + i * 16 + quad * 4 + r;
        int col = n0 + wn + j * 16 + l16;
        long long o = (long long)row * N + col;
        float sv = bf2f(Cb[o]);
        float v = acc[i][j][r] - sv * wdb[col];
        Cb[o] = f2bf(v > 0.f ? v : 0.f);
      }
    }
  }
}

// ------- transpose+shift+wdiag: S (TxN bf16) -> STs (NxT fp8), wd ----------
__global__ __launch_bounds__(256) void transpose_shift_wd_k(
    const uint16_t* __restrict__ S, uint8_t* __restrict__ STs,
    float* __restrict__ wd, int T, int N) {
  __shared__ uint16_t tile[65][72];
  __shared__ float wdl[64];
  int t0 = blockIdx.x * 64, n0 = blockIdx.y * 64, b = blockIdx.z;
  const uint16_t* Sb = S + (long long)b * T * N;
  for (int s = threadIdx.x; s < 65 * 8; s += 256) {
    int t = s >> 3, n8 = s & 7;
    u16x8 v = (u16x8){0, 0, 0, 0, 0, 0, 0, 0};
    if (t0 + t < T) v = *(const u16x8*)(Sb + (long long)(t0 + t) * N + n0 + n8 * 8);
    *(u16x8*)(&tile[t][n8 * 8]) = v;
  }
  if (threadIdx.x < 64) wdl[threadIdx.x] = 0.f;
  __syncthreads();
  uint8_t* STsb = STs + (long long)b * N * T;
  for (int s = threadIdx.x; s < 64 * 8; s += 256) {
    int n = s >> 3, t8 = s & 7;
    u8x8 c;
    float part = 0.f;
#pragma unroll
    for (int j = 0; j < 8; ++j) {
      float a = bf2f(tile[t8 * 8 + j][n]);
      float nb = bf2f(tile[t8 * 8 + j + 1][n]);
      c[j] = f2fp8(nb);
      part = fmaf(a, nb, part);
    }
    *(u8x8*)(STsb + (long long)(n0 + n) * T + t0 + t8 * 8) = c;
    atomicAdd(&wdl[n], part);
  }
  __syncthreads();
  if (threadIdx.x < 64)
    atomicAdd(&wd[(long long)b * N + n0 + threadIdx.x], wdl[threadIdx.x]);
}

// ---------------- shared selection core (ballot binary search) -------------
// Each wave holds the FULL row: k_[c][i] = key at index c*512 + lane*8 + i.
// Returns th (exact 64th-largest key), and uniform per-chunk stats.
struct SelInfo {
  unsigned th;
  int cg[4];    // count > th per chunk
  int tc[4];    // count == th per chunk
  int r;        // tie slots to take (64 - total greater)
  float inv;    // 1/l2norm of the selected set
};

__device__ __forceinline__ SelInfo select64(const int k_[4][8],
                                            const u16x8 v[4]) {
  unsigned lo = 0, hi = 0x7FFF;
  while (lo < hi) {
    unsigned mid = (lo + hi) >> 1;
    int cnt = 0;
#pragma unroll
    for (int c = 0; c < 4; ++c)
#pragma unroll
      for (int i = 0; i < 8; ++i)
        cnt += (int)__popcll(__ballot(k_[c][i] > (int)mid));
    if (cnt < 64) hi = mid; else lo = mid + 1;
  }
  SelInfo s;
  s.th = lo;
  const int th = (int)lo;
  int cgt = 0;
#pragma unroll
  for (int c = 0; c < 4; ++c) {
    int cg = 0, tc = 0;
#pragma unroll
    for (int i = 0; i < 8; ++i) {
      cg += (int)__popcll(__ballot(k_[c][i] > th));
      tc += (int)__popcll(__ballot(k_[c][i] == th));
    }
    s.cg[c] = cg;
    s.tc[c] = tc;
    cgt += cg;
  }
  s.r = 64 - cgt;
  // sum of squares over strictly-greater keys (per-lane then wave reduce)
  float ssq = 0.f;
#pragma unroll
  for (int c = 0; c < 4; ++c)
#pragma unroll
    for (int i = 0; i < 8; ++i)
      if (k_[c][i] > th) {
        float f = bf2f((unsigned)v[c][i]);
        ssq = fmaf(f, f, ssq);
      }
#pragma unroll
  for (int off = 32; off >= 1; off >>= 1) ssq += __shfl_xor(ssq, off, 64);
  float thf = bf2f(lo);
  float sumsq = ssq + (float)s.r * thf * thf;
  s.inv = 1.f / fmaxf(sqrtf(sumsq), 1e-10f);
  return s;
}

// ---------------- topk1: dense bf16 + fp8 outputs, no barriers -------------
__global__ __launch_bounds__(256) void topk1_k(
    const uint16_t* __restrict__ H, uint16_t* __restrict__ Sbf,
    uint8_t* __restrict__ Sf8) {
  const long long row = blockIdx.x;
  const uint16_t* h = H + row * 2048;
  const int lane = threadIdx.x & 63;
  const int wave = threadIdx.x >> 6;

  u16x8 v[4];
  int k_[4][8];
#pragma unroll
  for (int c = 0; c < 4; ++c) {
    v[c] = *(const u16x8*)(h + c * 512 + lane * 8);
#pragma unroll
    for (int i = 0; i < 8; ++i) k_[c][i] = (int)v[c][i];
  }
  SelInfo s = select64(k_, v);
  const int th = (int)s.th;

  // this wave writes chunk `wave`
  int tiebase = 0;
#pragma unroll
  for (int c = 0; c < 4; ++c)
    if (c < wave) tiebase += s.tc[c];
  unsigned long long tmask[8];
  int B = 0;
#pragma unroll
  for (int j = 0; j < 8; ++j) {
    tmask[j] = __ballot(k_[wave][j] == th);
    B += bits_below(tmask[j]);
  }
  u16x8 o16;
  u8x8 o8;
  int own = 0;
#pragma unroll
  for (int i = 0; i < 8; ++i) {
    int kv = k_[wave][i];
    bool ist = (kv == th);
    bool sel = (kv > th) || (ist && (tiebase + B + own) < s.r);
    if (ist) own++;
    float nv = sel ? bf2f((unsigned)v[wave][i]) * s.inv : 0.f;
    o16[i] = sel ? (unsigned short)f2bf(nv) : (unsigned short)0;
    o8[i] = sel ? f2fp8(nv) : (uint8_t)0;
  }
  *(u16x8*)(Sbf + row * 2048 + wave * 512 + lane * 8) = o16;
  *(u8x8*)(Sf8 + row * 2048 + wave * 512 + lane * 8) = o8;
}

// ------------- topk2 + final: one barrier, then gather -> out --------------
__global__ __launch_bounds__(256) void topk2_final_k(
    const uint16_t* __restrict__ H, const float* __restrict__ x,
    const float* __restrict__ g, const uint16_t* __restrict__ upTb,
    float* __restrict__ out) {
  const long long row = blockIdx.x;
  const uint16_t* h = H + row * 2048;
  const int tid = threadIdx.x;
  const int lane = tid & 63;
  const int wave = tid >> 6;

  __shared__ int sidx[64];
  __shared__ float sval[64];

  u16x8 v[4];
  int k_[4][8];
#pragma unroll
  for (int c = 0; c < 4; ++c) {
    v[c] = *(const u16x8*)(h + c * 512 + lane * 8);
#pragma unroll
    for (int i = 0; i < 8; ++i) k_[c][i] = (int)v[c][i];
  }
  SelInfo s = select64(k_, v);
  const int th = (int)s.th;

  // chunk slot bases (uniform): ties taken in global index order
  int sbase = 0, tiebase = 0;
  {
    int cum_t = 0, cum_slot = 0;
#pragma unroll
    for (int c = 0; c < 4; ++c) {
      int tk = s.r - cum_t;
      tk = tk < 0 ? 0 : (tk > s.tc[c] ? s.tc[c] : tk);
      if (c == wave) { sbase = cum_slot; tiebase = cum_t; }
      cum_t += s.tc[c];
      cum_slot += s.cg[c] + tk;
    }
  }
  // per-element selection for own chunk
  unsigned long long tmask[8];
  int B = 0;
#pragma unroll
  for (int j = 0; j < 8; ++j) {
    tmask[j] = __ballot(k_[wave][j] == th);
    B += bits_below(tmask[j]);
  }
  bool selb[8];
  {
    int own = 0;
#pragma unroll
    for (int i = 0; i < 8; ++i) {
      int kv = k_[wave][i];
      bool ist = (kv == th);
      selb[i] = (kv > th) || (ist && (tiebase + B + own) < s.r);
      if (ist) own++;
    }
  }
  unsigned long long smask[8];
  int SB = 0;
#pragma unroll
  for (int j = 0; j < 8; ++j) {
    smask[j] = __ballot(selb[j]);
    SB += bits_below(smask[j]);
  }
  {
    int prior = 0;
#pragma unroll
    for (int i = 0; i < 8; ++i) {
      if (selb[i]) {
        int slot = sbase + SB + prior;
        sidx[slot] = wave * 512 + lane * 8 + i;
        sval[slot] = bf2f((unsigned)v[wave][i]) * s.inv;
        prior++;
      }
    }
  }
  __syncthreads();

  // gather: out[row][col] = x + g * sum_j sval[j]*upTb[sidx[j]][col]
  const int col = tid * 2;
  float a0 = 0.f, a1 = 0.f;
#pragma unroll 8
  for (int j = 0; j < 64; ++j) {
    float w = sval[j];
    uint32_t pk = *(const uint32_t*)(upTb + (long long)sidx[j] * 512 + col);
    a0 = fmaf(w, bf2f(pk & 0xFFFFu), a0);
    a1 = fmaf(w, bf2f(pk >> 16), a1);
  }
  long long o = row * 512 + col;
  float2 xv = *(const float2*)(x + o);
  float2 gv = *(const float2*)(g + o);
  float2 rr;
  rr.x = xv.x + gv.x * a0;
  rr.y = xv.y + gv.y * a1;
  *(float2*)(out + o) = rr;
}

// ---------------------------------------------------------------------------
extern "C" void kernel_launch(void* const* d_in, const int* in_sizes, int n_in,
                              void* d_out, int out_size, void* d_ws, size_t ws_size,
                              hipStream_t stream) {
  const float* x = (const float*)d_in[0];
  const float* downW = (const float*)d_in[1];
  const float* upW = (const float*)d_in[2];
  const float* gateW = (const float*)d_in[3];
  const float* gateB = (const float*)d_in[4];
  float* out = (float*)d_out;

  const int B = 8, T = 2048, D = 512, N = 2048;
  const long long BT = (long long)B * T;
  const long long TN = (long long)T * N;
  const long long TD = (long long)T * D;

  char* base = (char*)d_ws;
  size_t off = 0;
  auto take = [&](size_t bytes) {
    size_t o = off;
    off += (bytes + 255) & ~(size_t)255;
    return o;
  };
  size_t o_xb = take((size_t)BT * D * 2);
  size_t o_dwb = take((size_t)N * D * 2);
  size_t o_gwb = take((size_t)D * D * 2);
  size_t o_upT = take((size_t)N * D * 2);
  const size_t fixed = off;
  const size_t perb = (size_t)TN * 2 + (size_t)TN * 2 + (size_t)TN +
                      (size_t)TN + (size_t)N * 4;
  int Bc = 1;
  if (ws_size >= fixed + 8 * perb) Bc = 8;
  else if (ws_size >= fixed + 4 * perb) Bc = 4;
  else if (ws_size >= fixed + 2 * perb) Bc = 2;

  uint16_t* xb = (uint16_t*)(base + o_xb);
  uint16_t* dwb = (uint16_t*)(base + o_dwb);
  uint16_t* gwb = (uint16_t*)(base + o_gwb);
  uint16_t* upTb = (uint16_t*)(base + o_upT);
  char* p = base + fixed;
  uint16_t* R1 = (uint16_t*)p; p += (size_t)TN * 2 * Bc;  // h (bf16) -> G (fp8)
  uint16_t* R2 = (uint16_t*)p; p += (size_t)TN * 2 * Bc;  // S (bf16) -> succ
  uint8_t* R3 = (uint8_t*)p;  p += (size_t)TN * Bc;       // STs fp8 -> g fp32
  uint8_t* R4 = (uint8_t*)p;  p += (size_t)TN * Bc;       // S fp8
  float* wd = (float*)p;

  cast_f32_bf16_k<<<2048, 256, 0, stream>>>(x, xb, BT * D);
  cast_f32_bf16_k<<<512, 256, 0, stream>>>(downW, dwb, (long long)N * D);
  cast_f32_bf16_k<<<128, 256, 0, stream>>>(gateW, gwb, (long long)D * D);
  transpose_upw_k<<<dim3(N / 32, D / 32), 256, 0, stream>>>(upW, upTb, D, N);

  const int ltri = 16 * 17 / 2;

  for (int b0 = 0; b0 < B; b0 += Bc) {
    const uint16_t* xc = xb + (long long)b0 * TD;
    gemm_bt_k<EPI_RELU_BF16><<<dim3(Bc * 16, 16, 1), 256, 0, stream>>>(
        xc, dwb, R1, nullptr, Bc * T, N, D);
    topk1_k<<<Bc * T, 256, 0, stream>>>(R1, R2, R4);
    zero_f32_k<<<(Bc * N + 255) / 256, 256, 0, stream>>>(wd, (long long)Bc * N);
    transpose_shift_wd_k<<<dim3(T / 64, N / 64, Bc), 256, 0, stream>>>(
        R2, R3, wd, T, N);
    gram_fp8_k<<<dim3(ltri, 1, Bc), 256, 0, stream>>>(
        R4, (uint8_t*)R1, TN, (long long)T * T);
    succ_fp8_k<<<dim3(16, 16, Bc), 256, 0, stream>>>(
        (const uint8_t*)R1, R3, R2, wd, (long long)T * T, TN, TN);
    gemm_bt_k<EPI_SIG><<<dim3(Bc * 16, D / 128, 1), 256, 0, stream>>>(
        xc, gwb, (float*)R3, gateB, Bc * T, D, D);
    topk2_final_k<<<Bc * T, 256, 0, stream>>>(
        R2, x + (long long)b0 * TD, (const float*)R3, upTb,
        out + (long long)b0 * TD);
  }
}

// Round 7
// 695.024 us; speedup vs baseline: 1.4876x; 1.4876x over previous
//
#include <hip/hip_runtime.h>
#include <stdint.h>
#include <math.h>

// ---------------------------------------------------------------------------
// HippocampalFastWeight on MI355X (gfx950)
// B=8, T=2048, D=512, N=2048, K_CA3=64
// Round 7: one-wave-per-row top-k (r6 had all 4 waves redundantly selecting
// the same row -> 4x wasted VALU at 92% VALUBusy). Ballot binary search is
// per-wave, so each wave now handles a distinct row; 4 rows per block.
// GEMM pipeline unchanged (fp8 gram/succ, bf16 h/gate, global_load_lds).
// ---------------------------------------------------------------------------

typedef __attribute__((ext_vector_type(8))) short bf16x8;
typedef __attribute__((ext_vector_type(8))) unsigned short u16x8;
typedef __attribute__((ext_vector_type(8))) unsigned char u8x8;
typedef __attribute__((ext_vector_type(4))) float f32x4;

#define GLD_LDS16(gp, lp)                                     \
  __builtin_amdgcn_global_load_lds(                           \
      (const __attribute__((address_space(1))) void*)(gp),    \
      (__attribute__((address_space(3))) void*)(lp), 16, 0, 0)

__device__ __forceinline__ uint16_t f2bf(float f) {
  uint32_t u = __float_as_uint(f);
  uint32_t r = u + 0x7FFFu + ((u >> 16) & 1u);
  return (uint16_t)(r >> 16);
}
__device__ __forceinline__ float bf2f(unsigned u) {
  return __uint_as_float(u << 16);
}

// f32 -> fp8 e4m3fn (inputs non-negative, < 448 here)
__device__ __forceinline__ uint8_t f2fp8(float f) {
#if __has_builtin(__builtin_amdgcn_cvt_pk_fp8_f32)
  return (uint8_t)(__builtin_amdgcn_cvt_pk_fp8_f32(f, 0.f, 0, false) & 0xFF);
#else
  if (!(f > 0.f)) return 0;
  if (f >= 448.f) return 0x7E;
  uint32_t u = __float_as_uint(f);
  int e = (int)((u >> 23) & 255) - 127;
  uint32_t m = u & 0x7FFFFFu;
  if (e < -6) {
    float q = f * 512.f;
    int qi = (int)(q + 0.5f);
    if (qi > 7) return 0x08;
    return (uint8_t)qi;
  }
  uint32_t keep = m >> 20;
  uint32_t rem = m & 0xFFFFFu;
  if (rem > 0x80000u || (rem == 0x80000u && (keep & 1))) keep++;
  uint32_t ee = (uint32_t)(e + 7);
  if (keep == 8) { keep = 0; ee++; }
  if (ee >= 16) return 0x7E;
  return (uint8_t)((ee << 3) | keep);
#endif
}

// bits of 64-bit mask strictly below this lane
__device__ __forceinline__ int bits_below(unsigned long long m) {
  return __builtin_amdgcn_mbcnt_hi((unsigned)(m >> 32),
                                   __builtin_amdgcn_mbcnt_lo((unsigned)m, 0));
}

// ------------------------------- cast --------------------------------------
__global__ __launch_bounds__(256) void cast_f32_bf16_k(
    const float* __restrict__ s, uint16_t* __restrict__ d, long long n) {
  long long i = (long long)blockIdx.x * 256 + threadIdx.x;
  long long stride = (long long)gridDim.x * 256;
  for (; i < n; i += stride) d[i] = f2bf(s[i]);
}

__global__ __launch_bounds__(256) void zero_f32_k(float* __restrict__ p, long long n) {
  long long i = (long long)blockIdx.x * 256 + threadIdx.x;
  if (i < n) p[i] = 0.f;
}

// ------------- transpose up_W (D x N fp32 -> N x D bf16) -------------------
__global__ __launch_bounds__(256) void transpose_upw_k(
    const float* __restrict__ src, uint16_t* __restrict__ dst, int D, int N) {
  __shared__ float t[32][33];
  int n0 = blockIdx.x * 32, d0 = blockIdx.y * 32;
  int lx = threadIdx.x & 31, ly = threadIdx.x >> 5;
#pragma unroll
  for (int r = 0; r < 4; ++r) {
    int d = d0 + ly + r * 8;
    t[ly + r * 8][lx] = src[(long long)d * N + n0 + lx];
  }
  __syncthreads();
#pragma unroll
  for (int r = 0; r < 4; ++r) {
    int n = n0 + ly + r * 8;
    dst[(long long)n * D + d0 + lx] = f2bf(t[lx][ly + r * 8]);
  }
}

// --------------------------- bf16 GEMM -------------------------------------
#define EPI_RELU_BF16 0
#define EPI_SIG 2

template <int EPI>
__global__ __launch_bounds__(256) void gemm_bt_k(
    const uint16_t* __restrict__ A, const uint16_t* __restrict__ B,
    void* __restrict__ Cv, const float* __restrict__ bias,
    int M, int N, int K) {
  __shared__ __align__(16) uint16_t As[128 * 32];
  __shared__ __align__(16) uint16_t Bs[128 * 32];
  const int tid = threadIdx.x;
  const int lane = tid & 63;
  const int wave = tid >> 6;
  const int m0 = blockIdx.x * 128;
  const int n0 = blockIdx.y * 128;
  const int wm = (wave & 1) * 64;
  const int wn = (wave >> 1) * 64;
  const int quad = lane >> 4;
  const int l16 = lane & 15;

  f32x4 acc[4][4];
#pragma unroll
  for (int i = 0; i < 4; ++i)
#pragma unroll
    for (int j = 0; j < 4; ++j) acc[i][j] = (f32x4){0.f, 0.f, 0.f, 0.f};

  const int srow = wave * 16 + (lane >> 2);
  const int sseg = lane & 3;
  const long long arow0 = (long long)(m0 + srow) * K + sseg * 8;
  const long long brow0 = (long long)(n0 + srow) * K + sseg * 8;

  for (int k0 = 0; k0 < K; k0 += 32) {
#pragma unroll
    for (int r = 0; r < 2; ++r) {
      GLD_LDS16(A + arow0 + (long long)r * 64 * K + k0,
                &As[(r * 64 + wave * 16) * 32]);
      GLD_LDS16(B + brow0 + (long long)r * 64 * K + k0,
                &Bs[(r * 64 + wave * 16) * 32]);
    }
    __syncthreads();
    bf16x8 af[4], bfr[4];
#pragma unroll
    for (int i = 0; i < 4; ++i)
      af[i] = *(const bf16x8*)(&As[(wm + i * 16 + l16) * 32 + quad * 8]);
#pragma unroll
    for (int j = 0; j < 4; ++j)
      bfr[j] = *(const bf16x8*)(&Bs[(wn + j * 16 + l16) * 32 + quad * 8]);
#pragma unroll
    for (int i = 0; i < 4; ++i)
#pragma unroll
      for (int j = 0; j < 4; ++j)
        acc[i][j] = __builtin_amdgcn_mfma_f32_16x16x32_bf16(af[i], bfr[j], acc[i][j], 0, 0, 0);
    __syncthreads();
  }

#pragma unroll
  for (int i = 0; i < 4; ++i) {
#pragma unroll
    for (int j = 0; j < 4; ++j) {
#pragma unroll
      for (int r = 0; r < 4; ++r) {
        int row = m0 + wm + i * 16 + quad * 4 + r;
        int col = n0 + wn + j * 16 + l16;
        float v = acc[i][j][r];
        if (EPI == EPI_RELU_BF16) {
          uint16_t* C = (uint16_t*)Cv;
          C[(long long)row * N + col] = f2bf(v > 0.f ? v : 0.f);
        } else {
          float* C = (float*)Cv;
          float z = v + bias[col];
          C[(long long)row * N + col] = 1.f / (1.f + __expf(-z));
        }
      }
    }
  }
}

// --------------------- fp8 Gram GEMM: G = S·S^T ----------------------------
__global__ __launch_bounds__(256) void gram_fp8_k(
    const uint8_t* __restrict__ S, uint8_t* __restrict__ G,
    long long sS, long long sG) {
  __shared__ __align__(16) uint8_t As[128 * 32];
  __shared__ __align__(16) uint8_t Bs[128 * 32];
  const int b = blockIdx.z;
  const uint8_t* Sb = S + (long long)b * sS;
  uint8_t* Gb = G + (long long)b * sG;
  int idx = blockIdx.x;
  int ti = 0;
  while ((ti + 1) * (ti + 2) / 2 <= idx) ti++;
  int tj = idx - ti * (ti + 1) / 2;
  const int m0 = ti * 128;
  const int n0 = tj * 128;
  const int tid = threadIdx.x;
  const int lane = tid & 63;
  const int wave = tid >> 6;
  const int wm = (wave & 1) * 64;
  const int wn = (wave >> 1) * 64;
  const int quad = lane >> 4;
  const int l16 = lane & 15;
  const int K = 2048, T = 2048;

  f32x4 acc[4][4];
#pragma unroll
  for (int i = 0; i < 4; ++i)
#pragma unroll
    for (int j = 0; j < 4; ++j) acc[i][j] = (f32x4){0.f, 0.f, 0.f, 0.f};

  const int srow = wave * 32 + (lane >> 1);
  const int shalf = lane & 1;
  const long long arow0 = (long long)(m0 + srow) * K + shalf * 16;
  const long long brow0 = (long long)(n0 + srow) * K + shalf * 16;

  for (int k0 = 0; k0 < K; k0 += 32) {
    GLD_LDS16(Sb + arow0 + k0, &As[wave * 1024]);
    GLD_LDS16(Sb + brow0 + k0, &Bs[wave * 1024]);
    __syncthreads();
    long af[4], bfr[4];
#pragma unroll
    for (int i = 0; i < 4; ++i)
      af[i] = *(const long*)(&As[(wm + i * 16 + l16) * 32 + quad * 8]);
#pragma unroll
    for (int j = 0; j < 4; ++j)
      bfr[j] = *(const long*)(&Bs[(wn + j * 16 + l16) * 32 + quad * 8]);
#pragma unroll
    for (int i = 0; i < 4; ++i)
#pragma unroll
      for (int j = 0; j < 4; ++j)
        acc[i][j] = __builtin_amdgcn_mfma_f32_16x16x32_fp8_fp8(af[i], bfr[j], acc[i][j], 0, 0, 0);
    __syncthreads();
  }

#pragma unroll
  for (int i = 0; i < 4; ++i) {
#pragma unroll
    for (int j = 0; j < 4; ++j) {
      uint8_t bv[4];
#pragma unroll
      for (int r = 0; r < 4; ++r) {
        int row = m0 + wm + i * 16 + quad * 4 + r;
        int col = n0 + wn + j * 16 + l16;
        uint8_t h = f2fp8(acc[i][j][r]);
        bv[r] = h;
        Gb[(long long)row * T + col] = h;
      }
      if (ti != tj) {
        int mrow = n0 + wn + j * 16 + l16;
        int mcol = m0 + wm + i * 16 + quad * 4;
        uchar4 pk = {bv[0], bv[1], bv[2], bv[3]};
        *(uchar4*)(&Gb[(long long)mrow * T + mcol]) = pk;
      }
    }
  }
}

// ------------------- fp8 succ GEMM: succ = relu(G@STs^T - S*wd) ------------
__global__ __launch_bounds__(256) void succ_fp8_k(
    const uint8_t* __restrict__ G, const uint8_t* __restrict__ STs,
    uint16_t* __restrict__ C, const float* __restrict__ wd,
    long long sG, long long sB, long long sC) {
  __shared__ __align__(16) uint8_t As[128 * 32];
  __shared__ __align__(16) uint8_t Bs[128 * 32];
  const int b = blockIdx.z;
  const uint8_t* Ab = G + (long long)b * sG;
  const uint8_t* Bb = STs + (long long)b * sB;
  uint16_t* Cb = C + (long long)b * sC;
  const float* wdb = wd + (long long)b * 2048;
  const int tid = threadIdx.x;
  const int lane = tid & 63;
  const int wave = tid >> 6;
  const int m0 = blockIdx.x * 128;
  const int n0 = blockIdx.y * 128;
  const int wm = (wave & 1) * 64;
  const int wn = (wave >> 1) * 64;
  const int quad = lane >> 4;
  const int l16 = lane & 15;
  const int K = 2048, N = 2048;

  f32x4 acc[4][4];
#pragma unroll
  for (int i = 0; i < 4; ++i)
#pragma unroll
    for (int j = 0; j < 4; ++j) acc[i][j] = (f32x4){0.f, 0.f, 0.f, 0.f};

  const int srow = wave * 32 + (lane >> 1);
  const int shalf = lane & 1;
  const long long arow0 = (long long)(m0 + srow) * K + shalf * 16;
  const long long brow0 = (long long)(n0 + srow) * K + shalf * 16;

  for (int k0 = 0; k0 < K; k0 += 32) {
    GLD_LDS16(Ab + arow0 + k0, &As[wave * 1024]);
    GLD_LDS16(Bb + brow0 + k0, &Bs[wave * 1024]);
    __syncthreads();
    long af[4], bfr[4];
#pragma unroll
    for (int i = 0; i < 4; ++i)
      af[i] = *(const long*)(&As[(wm + i * 16 + l16) * 32 + quad * 8]);
#pragma unroll
    for (int j = 0; j < 4; ++j)
      bfr[j] = *(const long*)(&Bs[(wn + j * 16 + l16) * 32 + quad * 8]);
#pragma unroll
    for (int i = 0; i < 4; ++i)
#pragma unroll
      for (int j = 0; j < 4; ++j)
        acc[i][j] = __builtin_amdgcn_mfma_f32_16x16x32_fp8_fp8(af[i], bfr[j], acc[i][j], 0, 0, 0);
    __syncthreads();
  }

#pragma unroll
  for (int i = 0; i < 4; ++i) {
#pragma unroll
    for (int j = 0; j < 4; ++j) {
#pragma unroll
      for (int r = 0; r < 4; ++r) {
        int row = m0 + wm + i * 16 + quad * 4 + r;
        int col = n0 + wn + j * 16 + l16;
        long long o = (long long)row * N + col;
        float sv = bf2f(Cb[o]);
        float v = acc[i][j][r] - sv * wdb[col];
        Cb[o] = f2bf(v > 0.f ? v : 0.f);
      }
    }
  }
}

// ------- transpose+shift+wdiag: S (TxN bf16) -> STs (NxT fp8), wd ----------
__global__ __launch_bounds__(256) void transpose_shift_wd_k(
    const uint16_t* __restrict__ S, uint8_t* __restrict__ STs,
    float* __restrict__ wd, int T, int N) {
  __shared__ uint16_t tile[65][72];
  __shared__ float wdl[64];
  int t0 = blockIdx.x * 64, n0 = blockIdx.y * 64, b = blockIdx.z;
  const uint16_t* Sb = S + (long long)b * T * N;
  for (int s = threadIdx.x; s < 65 * 8; s += 256) {
    int t = s >> 3, n8 = s & 7;
    u16x8 v = (u16x8){0, 0, 0, 0, 0, 0, 0, 0};
    if (t0 + t < T) v = *(const u16x8*)(Sb + (long long)(t0 + t) * N + n0 + n8 * 8);
    *(u16x8*)(&tile[t][n8 * 8]) = v;
  }
  if (threadIdx.x < 64) wdl[threadIdx.x] = 0.f;
  __syncthreads();
  uint8_t* STsb = STs + (long long)b * N * T;
  for (int s = threadIdx.x; s < 64 * 8; s += 256) {
    int n = s >> 3, t8 = s & 7;
    u8x8 c;
    float part = 0.f;
#pragma unroll
    for (int j = 0; j < 8; ++j) {
      float a = bf2f(tile[t8 * 8 + j][n]);
      float nb = bf2f(tile[t8 * 8 + j + 1][n]);
      c[j] = f2fp8(nb);
      part = fmaf(a, nb, part);
    }
    *(u8x8*)(STsb + (long long)(n0 + n) * T + t0 + t8 * 8) = c;
    atomicAdd(&wdl[n], part);
  }
  __syncthreads();
  if (threadIdx.x < 64)
    atomicAdd(&wd[(long long)b * N + n0 + threadIdx.x], wdl[threadIdx.x]);
}

// ---------------- shared selection core (ballot binary search) -------------
// Pure per-wave: the wave holds the FULL row as k_[c][i] = key at index
// c*512 + lane*8 + i. Finds exact 64th-largest key + uniform stats.
struct SelInfo {
  unsigned th;
  int cg[4];    // count > th per chunk
  int tc[4];    // count == th per chunk
  int r;        // tie slots to take (64 - total greater)
  float inv;    // 1/l2norm of the selected set
};

__device__ __forceinline__ SelInfo select64(const int k_[4][8],
                                            const u16x8 v[4]) {
  unsigned lo = 0, hi = 0x7FFF;
  while (lo < hi) {
    unsigned mid = (lo + hi) >> 1;
    int cnt = 0;
#pragma unroll
    for (int c = 0; c < 4; ++c)
#pragma unroll
      for (int i = 0; i < 8; ++i)
        cnt += (int)__popcll(__ballot(k_[c][i] > (int)mid));
    if (cnt < 64) hi = mid; else lo = mid + 1;
  }
  SelInfo s;
  s.th = lo;
  const int th = (int)lo;
  int cgt = 0;
#pragma unroll
  for (int c = 0; c < 4; ++c) {
    int cg = 0, tc = 0;
#pragma unroll
    for (int i = 0; i < 8; ++i) {
      cg += (int)__popcll(__ballot(k_[c][i] > th));
      tc += (int)__popcll(__ballot(k_[c][i] == th));
    }
    s.cg[c] = cg;
    s.tc[c] = tc;
    cgt += cg;
  }
  s.r = 64 - cgt;
  float ssq = 0.f;
#pragma unroll
  for (int c = 0; c < 4; ++c)
#pragma unroll
    for (int i = 0; i < 8; ++i)
      if (k_[c][i] > th) {
        float f = bf2f((unsigned)v[c][i]);
        ssq = fmaf(f, f, ssq);
      }
#pragma unroll
  for (int off = 32; off >= 1; off >>= 1) ssq += __shfl_xor(ssq, off, 64);
  float thf = bf2f(lo);
  float sumsq = ssq + (float)s.r * thf * thf;
  s.inv = 1.f / fmaxf(sqrtf(sumsq), 1e-10f);
  return s;
}

// ---------- topk1: one wave per row, dense bf16 + fp8 outputs --------------
__global__ __launch_bounds__(256) void topk1_k(
    const uint16_t* __restrict__ H, uint16_t* __restrict__ Sbf,
    uint8_t* __restrict__ Sf8) {
  const int lane = threadIdx.x & 63;
  const int wave = threadIdx.x >> 6;
  const long long row = (long long)blockIdx.x * 4 + wave;
  const uint16_t* h = H + row * 2048;

  u16x8 v[4];
  int k_[4][8];
#pragma unroll
  for (int c = 0; c < 4; ++c) {
    v[c] = *(const u16x8*)(h + c * 512 + lane * 8);
#pragma unroll
    for (int i = 0; i < 8; ++i) k_[c][i] = (int)v[c][i];
  }
  SelInfo s = select64(k_, v);
  const int th = (int)s.th;

  int tiebase = 0;
#pragma unroll
  for (int c = 0; c < 4; ++c) {
    int B = 0;
#pragma unroll
    for (int j = 0; j < 8; ++j)
      B += bits_below(__ballot(k_[c][j] == th));
    u16x8 o16;
    u8x8 o8;
    int own = 0;
#pragma unroll
    for (int i = 0; i < 8; ++i) {
      int kv = k_[c][i];
      bool ist = (kv == th);
      bool sel = (kv > th) || (ist && (tiebase + B + own) < s.r);
      if (ist) own++;
      float nv = sel ? bf2f((unsigned)v[c][i]) * s.inv : 0.f;
      o16[i] = sel ? (unsigned short)f2bf(nv) : (unsigned short)0;
      o8[i] = sel ? f2fp8(nv) : (uint8_t)0;
    }
    *(u16x8*)(Sbf + row * 2048 + c * 512 + lane * 8) = o16;
    *(u8x8*)(Sf8 + row * 2048 + c * 512 + lane * 8) = o8;
    tiebase += s.tc[c];
  }
}

// -------- topk2 + final: one wave per row, per-wave LDS slots, gather ------
__global__ __launch_bounds__(256) void topk2_final_k(
    const uint16_t* __restrict__ H, const float* __restrict__ x,
    const float* __restrict__ g, const uint16_t* __restrict__ upTb,
    float* __restrict__ out) {
  const int lane = threadIdx.x & 63;
  const int wave = threadIdx.x >> 6;
  const long long row = (long long)blockIdx.x * 4 + wave;
  const uint16_t* h = H + row * 2048;

  __shared__ int sidx[4][64];
  __shared__ float sval[4][64];

  u16x8 v[4];
  int k_[4][8];
#pragma unroll
  for (int c = 0; c < 4; ++c) {
    v[c] = *(const u16x8*)(h + c * 512 + lane * 8);
#pragma unroll
    for (int i = 0; i < 8; ++i) k_[c][i] = (int)v[c][i];
  }
  SelInfo s = select64(k_, v);
  const int th = (int)s.th;

  // compact selected (idx, val) into per-wave slots (order irrelevant: sum)
  int tiebase = 0;
  int cum = 0;
#pragma unroll
  for (int c = 0; c < 4; ++c) {
    int B = 0;
#pragma unroll
    for (int j = 0; j < 8; ++j)
      B += bits_below(__ballot(k_[c][j] == th));
    int own = 0;
#pragma unroll
    for (int i = 0; i < 8; ++i) {
      int kv = k_[c][i];
      bool ist = (kv == th);
      bool sel = (kv > th) || (ist && (tiebase + B + own) < s.r);
      if (ist) own++;
      unsigned long long sm = __ballot(sel);
      if (sel) {
        int slot = cum + bits_below(sm);
        sidx[wave][slot] = c * 512 + lane * 8 + i;
        sval[wave][slot] = bf2f((unsigned)v[c][i]) * s.inv;
      }
      cum += (int)__popcll(sm);
    }
    tiebase += s.tc[c];
  }
  __syncthreads();

  // gather: lane covers 8 contiguous cols; 64 upT rows, 16B loads (L2-hot)
  const int col0 = lane * 8;
  float a[8] = {0.f, 0.f, 0.f, 0.f, 0.f, 0.f, 0.f, 0.f};
#pragma unroll 4
  for (int j = 0; j < 64; ++j) {
    int idx = sidx[wave][j];
    float w = sval[wave][j];
    const u16x8 pk = *(const u16x8*)(upTb + (long long)idx * 512 + col0);
#pragma unroll
    for (int q = 0; q < 8; ++q) a[q] = fmaf(w, bf2f((unsigned)pk[q]), a[q]);
  }
  long long o = row * 512 + col0;
  const float4 xv0 = *(const float4*)(x + o);
  const float4 xv1 = *(const float4*)(x + o + 4);
  const float4 gv0 = *(const float4*)(g + o);
  const float4 gv1 = *(const float4*)(g + o + 4);
  float4 r0, r1;
  r0.x = xv0.x + gv0.x * a[0];
  r0.y = xv0.y + gv0.y * a[1];
  r0.z = xv0.z + gv0.z * a[2];
  r0.w = xv0.w + gv0.w * a[3];
  r1.x = xv1.x + gv1.x * a[4];
  r1.y = xv1.y + gv1.y * a[5];
  r1.z = xv1.z + gv1.z * a[6];
  r1.w = xv1.w + gv1.w * a[7];
  *(float4*)(out + o) = r0;
  *(float4*)(out + o + 4) = r1;
}

// ---------------------------------------------------------------------------
extern "C" void kernel_launch(void* const* d_in, const int* in_sizes, int n_in,
                              void* d_out, int out_size, void* d_ws, size_t ws_size,
                              hipStream_t stream) {
  const float* x = (const float*)d_in[0];
  const float* downW = (const float*)d_in[1];
  const float* upW = (const float*)d_in[2];
  const float* gateW = (const float*)d_in[3];
  const float* gateB = (const float*)d_in[4];
  float* out = (float*)d_out;

  const int B = 8, T = 2048, D = 512, N = 2048;
  const long long BT = (long long)B * T;
  const long long TN = (long long)T * N;
  const long long TD = (long long)T * D;

  char* base = (char*)d_ws;
  size_t off = 0;
  auto take = [&](size_t bytes) {
    size_t o = off;
    off += (bytes + 255) & ~(size_t)255;
    return o;
  };
  size_t o_xb = take((size_t)BT * D * 2);
  size_t o_dwb = take((size_t)N * D * 2);
  size_t o_gwb = take((size_t)D * D * 2);
  size_t o_upT = take((size_t)N * D * 2);
  const size_t fixed = off;
  const size_t perb = (size_t)TN * 2 + (size_t)TN * 2 + (size_t)TN +
                      (size_t)TN + (size_t)N * 4;
  int Bc = 1;
  if (ws_size >= fixed + 8 * perb) Bc = 8;
  else if (ws_size >= fixed + 4 * perb) Bc = 4;
  else if (ws_size >= fixed + 2 * perb) Bc = 2;

  uint16_t* xb = (uint16_t*)(base + o_xb);
  uint16_t* dwb = (uint16_t*)(base + o_dwb);
  uint16_t* gwb = (uint16_t*)(base + o_gwb);
  uint16_t* upTb = (uint16_t*)(base + o_upT);
  char* p = base + fixed;
  uint16_t* R1 = (uint16_t*)p; p += (size_t)TN * 2 * Bc;  // h (bf16) -> G (fp8)
  uint16_t* R2 = (uint16_t*)p; p += (size_t)TN * 2 * Bc;  // S (bf16) -> succ
  uint8_t* R3 = (uint8_t*)p;  p += (size_t)TN * Bc;       // STs fp8 -> g fp32
  uint8_t* R4 = (uint8_t*)p;  p += (size_t)TN * Bc;       // S fp8
  float* wd = (float*)p;

  cast_f32_bf16_k<<<2048, 256, 0, stream>>>(x, xb, BT * D);
  cast_f32_bf16_k<<<512, 256, 0, stream>>>(downW, dwb, (long long)N * D);
  cast_f32_bf16_k<<<128, 256, 0, stream>>>(gateW, gwb, (long long)D * D);
  transpose_upw_k<<<dim3(N / 32, D / 32), 256, 0, stream>>>(upW, upTb, D, N);

  const int ltri = 16 * 17 / 2;

  for (int b0 = 0; b0 < B; b0 += Bc) {
    const uint16_t* xc = xb + (long long)b0 * TD;
    gemm_bt_k<EPI_RELU_BF16><<<dim3(Bc * 16, 16, 1), 256, 0, stream>>>(
        xc, dwb, R1, nullptr, Bc * T, N, D);
    topk1_k<<<Bc * T / 4, 256, 0, stream>>>(R1, R2, R4);
    zero_f32_k<<<(Bc * N + 255) / 256, 256, 0, stream>>>(wd, (long long)Bc * N);
    transpose_shift_wd_k<<<dim3(T / 64, N / 64, Bc), 256, 0, stream>>>(
        R2, R3, wd, T, N);
    gram_fp8_k<<<dim3(ltri, 1, Bc), 256, 0, stream>>>(
        R4, (uint8_t*)R1, TN, (long long)T * T);
    succ_fp8_k<<<dim3(16, 16, Bc), 256, 0, stream>>>(
        (const uint8_t*)R1, R3, R2, wd, (long long)T * T, TN, TN);
    gemm_bt_k<EPI_SIG><<<dim3(Bc * 16, D / 128, 1), 256, 0, stream>>>(
        xc, gwb, (float*)R3, gateB, Bc * T, D, D);
    topk2_final_k<<<Bc * T / 4, 256, 0, stream>>>(
        R2, x + (long long)b0 * TD, (const float*)R3, upTb,
        out + (long long)b0 * TD);
  }
}